// Round 1
// baseline (68.002 us; speedup 1.0000x reference)
//
#include <hip/hip_runtime.h>
#include <hip/hip_bf16.h>

typedef __attribute__((ext_vector_type(8))) __bf16 bf16x8;
typedef __attribute__((ext_vector_type(4))) float f32x4;

#define B_   64
#define L_   512
#define HID_ 768
#define M_   128
#define R_   64
#define P_   8

// XOR-swizzle for row-major LDS tiles (ushort-index units, 8-elem aligned k).
__device__ __forceinline__ int swz(int row, int k, int stride) {
    return row * stride + (k ^ ((row & 7) << 3));
}

// ---------------- K0: evidence mask ----------------
__global__ __launch_bounds__(256) void k_evidence(const int* __restrict__ ctx,
                                                  const int* __restrict__ btw,
                                                  float* __restrict__ ev) {
    int b = blockIdx.x;
    __shared__ int any_b;
    if (threadIdx.x == 0) any_b = 0;
    __syncthreads();
    int l0 = threadIdx.x, l1 = threadIdx.x + 256;
    int v0 = btw[b * L_ + l0], v1 = btw[b * L_ + l1];
    if (v0 | v1) atomicOr(&any_b, 1);
    __syncthreads();
    const int* src = any_b ? btw : ctx;
    ev[b * L_ + l0] = src[b * L_ + l0] ? 1.0f : 0.0f;
    ev[b * L_ + l1] = src[b * L_ + l1] ? 1.0f : 0.0f;
}

// ---------------- Kw: transpose+cast proj_W -> Wt[n][k] bf16 ----------------
__global__ __launch_bounds__(256) void k_wt(const float* __restrict__ W,
                                            __bf16* __restrict__ Wt) {
    int idx = blockIdx.x * 256 + threadIdx.x;   // n*768 + k
    int n = idx / HID_, k = idx % HID_;
    Wt[idx] = (__bf16)W[k * M_ + n];
}

// ---------------- K1: build + normalize probes -> Q bf16 ----------------
__global__ __launch_bounds__(256) void k_probes(const float* __restrict__ lp,
                                                const float* __restrict__ sW,
                                                const float* __restrict__ oW,
                                                const float* __restrict__ dW,
                                                const int* __restrict__ st,
                                                const int* __restrict__ ot,
                                                const int* __restrict__ sf,
                                                __bf16* __restrict__ Q) {
    int t = threadIdx.x;
    int wave = t >> 6, lane = t & 63;
    int probe = blockIdx.x * 4 + wave;          // [0, 32768)
    int b  = probe >> 9;
    int rp = probe & 511;                        // r*8+p
    int m0 = lane, m1 = lane + 64;
    const float* lpp = lp + rp * M_;
    const float* s = sW + st[b] * M_;
    const float* o = oW + ot[b] * M_;
    const float* d = dW + sf[b] * M_;
    float q0 = lpp[m0] + s[m0] + o[m0] + d[m0];
    float q1 = lpp[m1] + s[m1] + o[m1] + d[m1];
    float ss = q0 * q0 + q1 * q1;
#pragma unroll
    for (int off = 1; off < 64; off <<= 1) ss += __shfl_xor(ss, off);
    float sc = 1.0f / fmaxf(sqrtf(ss), 1e-12f);
    Q[(size_t)probe * M_ + m0] = (__bf16)(q0 * sc);
    Q[(size_t)probe * M_ + m1] = (__bf16)(q1 * sc);
}

// ---------------- K2: D = l2norm(hidden @ W) via bf16 MFMA ----------------
__global__ __launch_bounds__(256) void k_proj(const float* __restrict__ hidden,
                                              const __bf16* __restrict__ Wt,
                                              __bf16* __restrict__ D) {
    __shared__ __align__(16) __bf16 Al[64 * 64];    // 8 KB  (rows x k)
    __shared__ __align__(16) __bf16 Bl[128 * 64];   // 16 KB (n    x k)
    const int t = threadIdx.x;
    const int lane = t & 63, w = t >> 6;
    const int rlo = lane & 15, g = lane >> 4;
    const int row0 = blockIdx.x * 64;

    f32x4 acc[8] = {};

    const int ar = t >> 2;            // A stage: row 0..63
    const int ac = (t & 3) * 16;      //          k offset 0/16/32/48
    const int bn = t >> 1;            // B stage: n 0..127
    const int bk = (t & 1) * 32;      //          k offset 0/32

    for (int kc = 0; kc < HID_; kc += 64) {
        {   // stage A (f32 -> bf16)
            const float* src = hidden + (size_t)(row0 + ar) * HID_ + kc + ac;
            float4 f0 = ((const float4*)src)[0];
            float4 f1 = ((const float4*)src)[1];
            float4 f2 = ((const float4*)src)[2];
            float4 f3 = ((const float4*)src)[3];
            bf16x8 v0, v1;
            v0[0]=(__bf16)f0.x; v0[1]=(__bf16)f0.y; v0[2]=(__bf16)f0.z; v0[3]=(__bf16)f0.w;
            v0[4]=(__bf16)f1.x; v0[5]=(__bf16)f1.y; v0[6]=(__bf16)f1.z; v0[7]=(__bf16)f1.w;
            v1[0]=(__bf16)f2.x; v1[1]=(__bf16)f2.y; v1[2]=(__bf16)f2.z; v1[3]=(__bf16)f2.w;
            v1[4]=(__bf16)f3.x; v1[5]=(__bf16)f3.y; v1[6]=(__bf16)f3.z; v1[7]=(__bf16)f3.w;
            *(bf16x8*)&Al[swz(ar, ac,     64)] = v0;
            *(bf16x8*)&Al[swz(ar, ac + 8, 64)] = v1;
        }
        {   // stage B (already bf16, n-major)
            const __bf16* src = Wt + (size_t)bn * HID_ + kc + bk;
#pragma unroll
            for (int q = 0; q < 4; ++q) {
                bf16x8 v = *(const bf16x8*)(src + q * 8);
                *(bf16x8*)&Bl[swz(bn, bk + q * 8, 64)] = v;
            }
        }
        __syncthreads();
#pragma unroll
        for (int s = 0; s < 2; ++s) {
            int k = s * 32 + g * 8;
            bf16x8 aF = *(const bf16x8*)&Al[swz(w * 16 + rlo, k, 64)];
#pragma unroll
            for (int c = 0; c < 8; ++c) {
                bf16x8 bF = *(const bf16x8*)&Bl[swz(c * 16 + rlo, k, 64)];
                acc[c] = __builtin_amdgcn_mfma_f32_16x16x32_bf16(aF, bF, acc[c], 0, 0, 0);
            }
        }
        __syncthreads();
    }

    // L2-normalize each output row, store bf16
    float ss[4] = {0.f, 0.f, 0.f, 0.f};
#pragma unroll
    for (int c = 0; c < 8; ++c)
#pragma unroll
        for (int r = 0; r < 4; ++r) ss[r] += acc[c][r] * acc[c][r];
#pragma unroll
    for (int r = 0; r < 4; ++r)
#pragma unroll
        for (int off = 1; off < 16; off <<= 1) ss[r] += __shfl_xor(ss[r], off);
    float sc[4];
#pragma unroll
    for (int r = 0; r < 4; ++r) sc[r] = 1.0f / fmaxf(sqrtf(ss[r]), 1e-12f);
#pragma unroll
    for (int c = 0; c < 8; ++c)
#pragma unroll
        for (int r = 0; r < 4; ++r) {
            int row = row0 + w * 16 + g * 4 + r;
            D[(size_t)row * M_ + c * 16 + rlo] = (__bf16)(acc[c][r] * sc[r]);
        }
}

// ---------------- K3: sim + masked max + sum -> logits ----------------
__global__ __launch_bounds__(256) void k_sim(const __bf16* __restrict__ Q,
                                             const __bf16* __restrict__ D,
                                             const float* __restrict__ ev,
                                             float* __restrict__ out) {
    __shared__ __align__(16) __bf16 Dl[128 * 128];  // 32 KB token chunk
    __shared__ float evl[L_];
    const int t = threadIdx.x;
    const int lane = t & 63, w = t >> 6;
    const int rlo = lane & 15, g = lane >> 4;
    const int b = blockIdx.y, pt = blockIdx.x;

    evl[t]       = ev[b * L_ + t];
    evl[t + 256] = ev[b * L_ + t + 256];

    // Q fragments for this wave's 16 probes: held in registers for all tokens
    const int probe = b * 512 + pt * 64 + w * 16 + rlo;
    bf16x8 qF[4];
#pragma unroll
    for (int ks = 0; ks < 4; ++ks)
        qF[ks] = *(const bf16x8*)(Q + (size_t)probe * M_ + ks * 32 + g * 8);

    float vmax[4] = {-1e30f, -1e30f, -1e30f, -1e30f};

    const int sr = t >> 1;           // stage: token row 0..127 in chunk
    const int sm = (t & 1) * 64;     //        m offset

    for (int tc = 0; tc < 4; ++tc) {
        const __bf16* src = D + (size_t)(b * L_ + tc * 128 + sr) * M_ + sm;
#pragma unroll
        for (int q = 0; q < 8; ++q) {
            bf16x8 v = *(const bf16x8*)(src + q * 8);
            *(bf16x8*)&Dl[swz(sr, sm + q * 8, 128)] = v;
        }
        __syncthreads();
#pragma unroll
        for (int tt = 0; tt < 8; ++tt) {
            f32x4 acc = {};
#pragma unroll
            for (int ks = 0; ks < 4; ++ks) {
                bf16x8 bF = *(const bf16x8*)&Dl[swz(tt * 16 + rlo, ks * 32 + g * 8, 128)];
                acc = __builtin_amdgcn_mfma_f32_16x16x32_bf16(qF[ks], bF, acc, 0, 0, 0);
            }
            float e = evl[tc * 128 + tt * 16 + rlo];
#pragma unroll
            for (int r = 0; r < 4; ++r) {
                float sv = (e > 0.5f) ? acc[r] : -1e4f;
                vmax[r] = fmaxf(vmax[r], sv);
            }
        }
        __syncthreads();
    }

    // max over the 16 token-columns held across the 16-lane group
#pragma unroll
    for (int r = 0; r < 4; ++r)
#pragma unroll
        for (int off = 1; off < 16; off <<= 1)
            vmax[r] = fmaxf(vmax[r], __shfl_xor(vmax[r], off));

    float psum = 0.f;
#pragma unroll
    for (int r = 0; r < 4; ++r)
        psum += (vmax[r] > -1000.0f) ? vmax[r] : 0.0f;

    // pair the two 16-lane groups holding the same r (probes 8k..8k+7)
    float rtot = psum + __shfl_xor(psum, 16);
    if ((lane & 31) == 0) {
        int rr = pt * 8 + w * 2 + (g >> 1);
        out[b * R_ + rr] = rtot;
    }
}

// ---------------- launcher ----------------
extern "C" void kernel_launch(void* const* d_in, const int* in_sizes, int n_in,
                              void* d_out, int out_size, void* d_ws, size_t ws_size,
                              hipStream_t stream) {
    const float* hidden = (const float*)d_in[0];
    const int*   ctx    = (const int*)d_in[1];
    const int*   btw    = (const int*)d_in[2];
    const int*   st     = (const int*)d_in[3];
    const int*   ot     = (const int*)d_in[4];
    const int*   sf     = (const int*)d_in[5];
    const float* W      = (const float*)d_in[6];
    const float* lp     = (const float*)d_in[7];
    const float* sW     = (const float*)d_in[8];
    const float* oW     = (const float*)d_in[9];
    const float* dW     = (const float*)d_in[10];
    float* out = (float*)d_out;

    char* ws = (char*)d_ws;
    float*  ev = (float*)ws;                                   // 131072 B
    __bf16* Wt = (__bf16*)(ws + 131072);                       // 196608 B
    __bf16* Q  = (__bf16*)(ws + 327680);                       // 8 MB
    __bf16* D  = (__bf16*)(ws + 327680 + 8388608);             // 8 MB

    k_evidence<<<B_, 256, 0, stream>>>(ctx, btw, ev);
    k_wt      <<<(HID_ * M_) / 256, 256, 0, stream>>>(W, Wt);
    k_probes  <<<(B_ * R_ * P_) / 4, 256, 0, stream>>>(lp, sW, oW, dW, st, ot, sf, Q);
    k_proj    <<<(B_ * L_) / 64, 256, 0, stream>>>(hidden, Wt, D);
    k_sim     <<<dim3(8, B_), 256, 0, stream>>>(Q, D, ev, out);
}

// Round 2
// 59.547 us; speedup vs baseline: 1.1420x; 1.1420x over previous
//
#include <hip/hip_runtime.h>
#include <hip/hip_bf16.h>

typedef __attribute__((ext_vector_type(8))) __bf16 bf16x8;
typedef __attribute__((ext_vector_type(4))) float f32x4;

#define B_   64
#define L_   512
#define HID_ 768
#define M_   128
#define R_   64
#define P_   8

// XOR-swizzle for row-major LDS tiles (ushort-index units, 8-elem aligned k).
__device__ __forceinline__ int swz(int row, int k, int stride) {
    return row * stride + (k ^ ((row & 7) << 3));
}

// ---------------- Kw: transpose+cast proj_W -> Wt[n][k] bf16 ----------------
__global__ __launch_bounds__(256) void k_wt(const float* __restrict__ W,
                                            __bf16* __restrict__ Wt) {
    int idx = blockIdx.x * 256 + threadIdx.x;   // n*768 + k
    int n = idx / HID_, k = idx % HID_;
    Wt[idx] = (__bf16)W[k * M_ + n];
}

// ---------------- K2: D = l2norm(hidden @ W) via bf16 MFMA ----------------
__global__ __launch_bounds__(256) void k_proj(const float* __restrict__ hidden,
                                              const __bf16* __restrict__ Wt,
                                              __bf16* __restrict__ D) {
    __shared__ __align__(16) __bf16 Al[64 * 64];    // 8 KB  (rows x k)
    __shared__ __align__(16) __bf16 Bl[128 * 64];   // 16 KB (n    x k)
    const int t = threadIdx.x;
    const int lane = t & 63, w = t >> 6;
    const int rlo = lane & 15, g = lane >> 4;
    const int row0 = blockIdx.x * 64;

    f32x4 acc[8] = {};

    const int ar = t >> 2;            // A stage: row 0..63
    const int ac = (t & 3) * 16;      //          k offset 0/16/32/48
    const int bn = t >> 1;            // B stage: n 0..127
    const int bk = (t & 1) * 32;      //          k offset 0/32

    for (int kc = 0; kc < HID_; kc += 64) {
        {   // stage A (f32 -> bf16)
            const float* src = hidden + (size_t)(row0 + ar) * HID_ + kc + ac;
            float4 f0 = ((const float4*)src)[0];
            float4 f1 = ((const float4*)src)[1];
            float4 f2 = ((const float4*)src)[2];
            float4 f3 = ((const float4*)src)[3];
            bf16x8 v0, v1;
            v0[0]=(__bf16)f0.x; v0[1]=(__bf16)f0.y; v0[2]=(__bf16)f0.z; v0[3]=(__bf16)f0.w;
            v0[4]=(__bf16)f1.x; v0[5]=(__bf16)f1.y; v0[6]=(__bf16)f1.z; v0[7]=(__bf16)f1.w;
            v1[0]=(__bf16)f2.x; v1[1]=(__bf16)f2.y; v1[2]=(__bf16)f2.z; v1[3]=(__bf16)f2.w;
            v1[4]=(__bf16)f3.x; v1[5]=(__bf16)f3.y; v1[6]=(__bf16)f3.z; v1[7]=(__bf16)f3.w;
            *(bf16x8*)&Al[swz(ar, ac,     64)] = v0;
            *(bf16x8*)&Al[swz(ar, ac + 8, 64)] = v1;
        }
        {   // stage B (already bf16, n-major)
            const __bf16* src = Wt + (size_t)bn * HID_ + kc + bk;
#pragma unroll
            for (int q = 0; q < 4; ++q) {
                bf16x8 v = *(const bf16x8*)(src + q * 8);
                *(bf16x8*)&Bl[swz(bn, bk + q * 8, 64)] = v;
            }
        }
        __syncthreads();
#pragma unroll
        for (int s = 0; s < 2; ++s) {
            int k = s * 32 + g * 8;
            bf16x8 aF = *(const bf16x8*)&Al[swz(w * 16 + rlo, k, 64)];
#pragma unroll
            for (int c = 0; c < 8; ++c) {
                bf16x8 bF = *(const bf16x8*)&Bl[swz(c * 16 + rlo, k, 64)];
                acc[c] = __builtin_amdgcn_mfma_f32_16x16x32_bf16(aF, bF, acc[c], 0, 0, 0);
            }
        }
        __syncthreads();
    }

    // L2-normalize each output row, store bf16
    float ss[4] = {0.f, 0.f, 0.f, 0.f};
#pragma unroll
    for (int c = 0; c < 8; ++c)
#pragma unroll
        for (int r = 0; r < 4; ++r) ss[r] += acc[c][r] * acc[c][r];
#pragma unroll
    for (int r = 0; r < 4; ++r)
#pragma unroll
        for (int off = 1; off < 16; off <<= 1) ss[r] += __shfl_xor(ss[r], off);
    float sc[4];
#pragma unroll
    for (int r = 0; r < 4; ++r) sc[r] = 1.0f / fmaxf(sqrtf(ss[r]), 1e-12f);
#pragma unroll
    for (int c = 0; c < 8; ++c)
#pragma unroll
        for (int r = 0; r < 4; ++r) {
            int row = row0 + w * 16 + g * 4 + r;
            D[(size_t)row * M_ + c * 16 + rlo] = (__bf16)(acc[c][r] * sc[r]);
        }
}

// -------- K3: fused probes + evidence + sim + masked max + sum -> logits ----
__global__ __launch_bounds__(256) void k_sim(const float* __restrict__ lp,
                                             const float* __restrict__ sW,
                                             const float* __restrict__ oW,
                                             const float* __restrict__ dW,
                                             const int* __restrict__ st,
                                             const int* __restrict__ ot,
                                             const int* __restrict__ sf,
                                             const int* __restrict__ ctx,
                                             const int* __restrict__ btw,
                                             const __bf16* __restrict__ D,
                                             float* __restrict__ out) {
    __shared__ __align__(16) __bf16 Dl[128 * 128];  // 32 KB token chunk
    __shared__ float evl[L_];
    __shared__ int anyf;
    const int t = threadIdx.x;
    const int lane = t & 63, w = t >> 6;
    const int rlo = lane & 15, g = lane >> 4;
    const int b = blockIdx.y, pt = blockIdx.x;

    // ---- evidence (fused) ----
    if (t == 0) anyf = 0;
    __syncthreads();
    int v0 = btw[b * L_ + t], v1 = btw[b * L_ + t + 256];
    int c0 = ctx[b * L_ + t], c1 = ctx[b * L_ + t + 256];
    if (v0 | v1) anyf = 1;          // benign race: all writers store 1
    __syncthreads();
    const int any = anyf;
    evl[t]       = (any ? v0 : c0) ? 1.0f : 0.0f;
    evl[t + 256] = (any ? v1 : c1) ? 1.0f : 0.0f;

    // ---- probe build (fused, in-register) ----
    // This lane's A-fragment probe row: pt*64 + w*16 + rlo; elements
    // m = ks*32 + g*8 .. +8 for ks=0..3 (exactly the MFMA A layout).
    const int sb = st[b], ob = ot[b], db = sf[b];
    const float* lpp = lp + (size_t)(pt * 64 + w * 16 + rlo) * M_;
    const float* sv  = sW + sb * M_;
    const float* ov  = oW + ob * M_;
    const float* dv  = dW + db * M_;
    float qv[32];
    float ssq = 0.f;
#pragma unroll
    for (int ks = 0; ks < 4; ++ks) {
        const int m0 = ks * 32 + g * 8;
#pragma unroll
        for (int h = 0; h < 2; ++h) {
            float4 a  = *(const float4*)(lpp + m0 + h * 4);
            float4 s4 = *(const float4*)(sv  + m0 + h * 4);
            float4 o4 = *(const float4*)(ov  + m0 + h * 4);
            float4 d4 = *(const float4*)(dv  + m0 + h * 4);
            float x0 = a.x + s4.x + o4.x + d4.x;
            float x1 = a.y + s4.y + o4.y + d4.y;
            float x2 = a.z + s4.z + o4.z + d4.z;
            float x3 = a.w + s4.w + o4.w + d4.w;
            qv[ks * 8 + h * 4 + 0] = x0;
            qv[ks * 8 + h * 4 + 1] = x1;
            qv[ks * 8 + h * 4 + 2] = x2;
            qv[ks * 8 + h * 4 + 3] = x3;
            ssq += x0 * x0 + x1 * x1 + x2 * x2 + x3 * x3;
        }
    }
    // reduce across the 4 lanes (g=0..3) holding the same probe row
    ssq += __shfl_xor(ssq, 16);
    ssq += __shfl_xor(ssq, 32);
    const float scq = 1.0f / fmaxf(sqrtf(ssq), 1e-12f);
    bf16x8 qF[4];
#pragma unroll
    for (int ks = 0; ks < 4; ++ks)
#pragma unroll
        for (int j = 0; j < 8; ++j)
            qF[ks][j] = (__bf16)(qv[ks * 8 + j] * scq);

    // ---- MaxSim main loop ----
    float vmax[4] = {-1e30f, -1e30f, -1e30f, -1e30f};

    const int sr = t >> 1;           // stage: token row 0..127 in chunk
    const int sm = (t & 1) * 64;     //        m offset

    for (int tc = 0; tc < 4; ++tc) {
        const __bf16* src = D + (size_t)(b * L_ + tc * 128 + sr) * M_ + sm;
#pragma unroll
        for (int q = 0; q < 8; ++q) {
            bf16x8 v = *(const bf16x8*)(src + q * 8);
            *(bf16x8*)&Dl[swz(sr, sm + q * 8, 128)] = v;
        }
        __syncthreads();
#pragma unroll
        for (int tt = 0; tt < 8; ++tt) {
            f32x4 acc = {};
#pragma unroll
            for (int ks = 0; ks < 4; ++ks) {
                bf16x8 bF = *(const bf16x8*)&Dl[swz(tt * 16 + rlo, ks * 32 + g * 8, 128)];
                acc = __builtin_amdgcn_mfma_f32_16x16x32_bf16(qF[ks], bF, acc, 0, 0, 0);
            }
            float e = evl[tc * 128 + tt * 16 + rlo];
#pragma unroll
            for (int r = 0; r < 4; ++r) {
                float sv2 = (e > 0.5f) ? acc[r] : -1e4f;
                vmax[r] = fmaxf(vmax[r], sv2);
            }
        }
        __syncthreads();
    }

    // max over the 16 token-columns held across the 16-lane group
#pragma unroll
    for (int r = 0; r < 4; ++r)
#pragma unroll
        for (int off = 1; off < 16; off <<= 1)
            vmax[r] = fmaxf(vmax[r], __shfl_xor(vmax[r], off));

    float psum = 0.f;
#pragma unroll
    for (int r = 0; r < 4; ++r)
        psum += (vmax[r] > -1000.0f) ? vmax[r] : 0.0f;

    // pair the two 16-lane groups holding the same r (probes 8k..8k+7)
    float rtot = psum + __shfl_xor(psum, 16);
    if ((lane & 31) == 0) {
        int rr = pt * 8 + w * 2 + (g >> 1);
        out[b * R_ + rr] = rtot;
    }
}

// ---------------- launcher ----------------
extern "C" void kernel_launch(void* const* d_in, const int* in_sizes, int n_in,
                              void* d_out, int out_size, void* d_ws, size_t ws_size,
                              hipStream_t stream) {
    const float* hidden = (const float*)d_in[0];
    const int*   ctx    = (const int*)d_in[1];
    const int*   btw    = (const int*)d_in[2];
    const int*   st     = (const int*)d_in[3];
    const int*   ot     = (const int*)d_in[4];
    const int*   sf     = (const int*)d_in[5];
    const float* W      = (const float*)d_in[6];
    const float* lp     = (const float*)d_in[7];
    const float* sW     = (const float*)d_in[8];
    const float* oW     = (const float*)d_in[9];
    const float* dW     = (const float*)d_in[10];
    float* out = (float*)d_out;

    char* ws = (char*)d_ws;
    __bf16* Wt = (__bf16*)ws;                       // 196608 B
    __bf16* D  = (__bf16*)(ws + 196608);            // 8 MB

    k_wt  <<<(HID_ * M_) / 256, 256, 0, stream>>>(W, Wt);
    k_proj<<<(B_ * L_) / 64, 256, 0, stream>>>(hidden, Wt, D);
    k_sim <<<dim3(8, B_), 256, 0, stream>>>(lp, sW, oW, dW, st, ot, sf, ctx, btw, D, out);
}

// Round 3
// 50.290 us; speedup vs baseline: 1.3522x; 1.1841x over previous
//
#include <hip/hip_runtime.h>
#include <hip/hip_bf16.h>

typedef __attribute__((ext_vector_type(8))) __bf16 bf16x8;
typedef __attribute__((ext_vector_type(4))) float f32x4;

#define B_   64
#define L_   512
#define HID_ 768
#define M_   128
#define R_   64
#define P_   8

// XOR-swizzle for row-major LDS tiles (ushort-index units, 8-elem aligned k).
__device__ __forceinline__ int swz(int row, int k, int stride) {
    return row * stride + (k ^ ((row & 7) << 3));
}

// async 16B global -> LDS (linear dest: wave-uniform base + lane*16)
#define GLL16(gp, lp)                                                        \
    __builtin_amdgcn_global_load_lds(                                        \
        (const __attribute__((address_space(1))) void*)(gp),                 \
        (__attribute__((address_space(3))) void*)(lp), 16, 0, 0)

// ---- Kw: transpose+cast proj_W -> Wt, PRE-SWIZZLED per 64-k chunk --------
// Wt[c*8192 + n*64 + (kk ^ ((n&7)<<3))] = W[(c*64+kk)*128 + n]
__global__ __launch_bounds__(256) void k_wt(const float* __restrict__ W,
                                            __bf16* __restrict__ Wt) {
    int idx = blockIdx.x * 256 + threadIdx.x;   // k*128 + n  (coalesced read)
    int k = idx >> 7, n = idx & 127;
    int c = k >> 6, kk = k & 63;
    Wt[c * 8192 + n * 64 + (kk ^ ((n & 7) << 3))] = (__bf16)W[idx];
}

// ---- K2: D = l2norm(hidden @ W), bf16 MFMA, 2-phase pipeline -------------
// Stores D PRE-SWIZZLED: D[row*128 + (col ^ ((row&7)<<3))]
__global__ __launch_bounds__(256) void k_proj(const float* __restrict__ hidden,
                                              const __bf16* __restrict__ Wt,
                                              __bf16* __restrict__ D) {
    __shared__ __align__(16) __bf16 Al[2][64 * 64];     // 2 x 8 KB
    __shared__ __align__(16) __bf16 Bl[2][128 * 64];    // 2 x 16 KB
    const int t = threadIdx.x;
    const int lane = t & 63, w = t >> 6;
    const int rlo = lane & 15, g = lane >> 4;
    const int row0 = blockIdx.x * 64;

    f32x4 acc[8] = {};

    const int ar = t >> 2;            // A stage: row 0..63
    const int ac = (t & 3) * 16;      //          k offset 0/16/32/48
    const float* arow = hidden + (size_t)(row0 + ar) * HID_ + ac;

    // ---- prologue: stage chunk 0 into buffer 0 ----
#pragma unroll
    for (int q = 0; q < 4; ++q)
        GLL16(Wt + q * 2048 + w * 512 + lane * 8, &Bl[0][q * 2048 + w * 512]);
    {
        float4 f0 = ((const float4*)arow)[0];
        float4 f1 = ((const float4*)arow)[1];
        float4 f2 = ((const float4*)arow)[2];
        float4 f3 = ((const float4*)arow)[3];
        bf16x8 v0, v1;
        v0[0]=(__bf16)f0.x; v0[1]=(__bf16)f0.y; v0[2]=(__bf16)f0.z; v0[3]=(__bf16)f0.w;
        v0[4]=(__bf16)f1.x; v0[5]=(__bf16)f1.y; v0[6]=(__bf16)f1.z; v0[7]=(__bf16)f1.w;
        v1[0]=(__bf16)f2.x; v1[1]=(__bf16)f2.y; v1[2]=(__bf16)f2.z; v1[3]=(__bf16)f2.w;
        v1[4]=(__bf16)f3.x; v1[5]=(__bf16)f3.y; v1[6]=(__bf16)f3.z; v1[7]=(__bf16)f3.w;
        *(bf16x8*)&Al[0][swz(ar, ac,     64)] = v0;
        *(bf16x8*)&Al[0][swz(ar, ac + 8, 64)] = v1;
    }
    __syncthreads();

    for (int ci = 0; ci < 12; ++ci) {
        const int cur = ci & 1;
        const bool pre = ci < 11;
        float4 f0, f1, f2, f3;
        if (pre) {   // issue next-chunk loads BEFORE compute
#pragma unroll
            for (int q = 0; q < 4; ++q)
                GLL16(Wt + (ci + 1) * 8192 + q * 2048 + w * 512 + lane * 8,
                      &Bl[cur ^ 1][q * 2048 + w * 512]);
            const float* src = arow + (ci + 1) * 64;
            f0 = ((const float4*)src)[0];
            f1 = ((const float4*)src)[1];
            f2 = ((const float4*)src)[2];
            f3 = ((const float4*)src)[3];
        }
#pragma unroll
        for (int s = 0; s < 2; ++s) {
            int k = s * 32 + g * 8;
            bf16x8 aF = *(const bf16x8*)&Al[cur][swz(w * 16 + rlo, k, 64)];
#pragma unroll
            for (int c = 0; c < 8; ++c) {
                bf16x8 bF = *(const bf16x8*)&Bl[cur][swz(c * 16 + rlo, k, 64)];
                acc[c] = __builtin_amdgcn_mfma_f32_16x16x32_bf16(aF, bF, acc[c], 0, 0, 0);
            }
        }
        if (pre) {   // write-late: cvt + ds_write after compute
            bf16x8 v0, v1;
            v0[0]=(__bf16)f0.x; v0[1]=(__bf16)f0.y; v0[2]=(__bf16)f0.z; v0[3]=(__bf16)f0.w;
            v0[4]=(__bf16)f1.x; v0[5]=(__bf16)f1.y; v0[6]=(__bf16)f1.z; v0[7]=(__bf16)f1.w;
            v1[0]=(__bf16)f2.x; v1[1]=(__bf16)f2.y; v1[2]=(__bf16)f2.z; v1[3]=(__bf16)f2.w;
            v1[4]=(__bf16)f3.x; v1[5]=(__bf16)f3.y; v1[6]=(__bf16)f3.z; v1[7]=(__bf16)f3.w;
            *(bf16x8*)&Al[cur ^ 1][swz(ar, ac,     64)] = v0;
            *(bf16x8*)&Al[cur ^ 1][swz(ar, ac + 8, 64)] = v1;
        }
        __syncthreads();
    }

    // L2-normalize each output row, store bf16 PRE-SWIZZLED
    float ss[4] = {0.f, 0.f, 0.f, 0.f};
#pragma unroll
    for (int c = 0; c < 8; ++c)
#pragma unroll
        for (int r = 0; r < 4; ++r) ss[r] += acc[c][r] * acc[c][r];
#pragma unroll
    for (int r = 0; r < 4; ++r)
#pragma unroll
        for (int off = 1; off < 16; off <<= 1) ss[r] += __shfl_xor(ss[r], off);
    float sc[4];
#pragma unroll
    for (int r = 0; r < 4; ++r) sc[r] = 1.0f / fmaxf(sqrtf(ss[r]), 1e-12f);
#pragma unroll
    for (int c = 0; c < 8; ++c)
#pragma unroll
        for (int r = 0; r < 4; ++r) {
            int row = row0 + w * 16 + g * 4 + r;
            int col = c * 16 + rlo;
            D[(size_t)row * M_ + (col ^ ((row & 7) << 3))] = (__bf16)(acc[c][r] * sc[r]);
        }
}

// ---- K3: fused probes + evidence + sim + masked max + sum -> logits ------
__global__ __launch_bounds__(256) void k_sim(const float* __restrict__ lp,
                                             const float* __restrict__ sW,
                                             const float* __restrict__ oW,
                                             const float* __restrict__ dW,
                                             const int* __restrict__ st,
                                             const int* __restrict__ ot,
                                             const int* __restrict__ sf,
                                             const int* __restrict__ ctx,
                                             const int* __restrict__ btw,
                                             const __bf16* __restrict__ D,
                                             float* __restrict__ out) {
    __shared__ __align__(16) __bf16 Dl[2][128 * 128];   // 2 x 32 KB
    __shared__ float evl[L_];
    __shared__ int anyf;
    const int t = threadIdx.x;
    const int lane = t & 63, w = t >> 6;
    const int rlo = lane & 15, g = lane >> 4;
    const int b = blockIdx.y, pt = blockIdx.x;

    const __bf16* Db = D + (size_t)b * L_ * M_;

    // ---- issue chunk-0 DMA first (overlaps probe build) ----
#pragma unroll
    for (int q = 0; q < 8; ++q)
        GLL16(Db + q * 2048 + w * 512 + lane * 8, &Dl[0][q * 2048 + w * 512]);

    // ---- evidence (fused) ----
    if (t == 0) anyf = 0;
    __syncthreads();
    int v0 = btw[b * L_ + t], v1 = btw[b * L_ + t + 256];
    int c0 = ctx[b * L_ + t], c1 = ctx[b * L_ + t + 256];
    if (v0 | v1) anyf = 1;          // benign race: all writers store 1
    __syncthreads();
    const int any = anyf;
    evl[t]       = (any ? v0 : c0) ? 1.0f : 0.0f;
    evl[t + 256] = (any ? v1 : c1) ? 1.0f : 0.0f;

    // ---- probe build (fused, in-register) ----
    const int sb = st[b], ob = ot[b], db = sf[b];
    const float* lpp = lp + (size_t)(pt * 64 + w * 16 + rlo) * M_;
    const float* sv  = sW + sb * M_;
    const float* ov  = oW + ob * M_;
    const float* dv  = dW + db * M_;
    float qv[32];
    float ssq = 0.f;
#pragma unroll
    for (int ks = 0; ks < 4; ++ks) {
        const int m0 = ks * 32 + g * 8;
#pragma unroll
        for (int h = 0; h < 2; ++h) {
            float4 a  = *(const float4*)(lpp + m0 + h * 4);
            float4 s4 = *(const float4*)(sv  + m0 + h * 4);
            float4 o4 = *(const float4*)(ov  + m0 + h * 4);
            float4 d4 = *(const float4*)(dv  + m0 + h * 4);
            float x0 = a.x + s4.x + o4.x + d4.x;
            float x1 = a.y + s4.y + o4.y + d4.y;
            float x2 = a.z + s4.z + o4.z + d4.z;
            float x3 = a.w + s4.w + o4.w + d4.w;
            qv[ks * 8 + h * 4 + 0] = x0;
            qv[ks * 8 + h * 4 + 1] = x1;
            qv[ks * 8 + h * 4 + 2] = x2;
            qv[ks * 8 + h * 4 + 3] = x3;
            ssq += x0 * x0 + x1 * x1 + x2 * x2 + x3 * x3;
        }
    }
    ssq += __shfl_xor(ssq, 16);
    ssq += __shfl_xor(ssq, 32);
    const float scq = 1.0f / fmaxf(sqrtf(ssq), 1e-12f);
    bf16x8 qF[4];
#pragma unroll
    for (int ks = 0; ks < 4; ++ks)
#pragma unroll
        for (int j = 0; j < 8; ++j)
            qF[ks][j] = (__bf16)(qv[ks * 8 + j] * scq);

    __syncthreads();   // Dl[0] + evl ready

    // ---- MaxSim main loop: 1 barrier/chunk, DMA next while computing ----
    float vmax[4] = {-1e30f, -1e30f, -1e30f, -1e30f};

    for (int tc = 0; tc < 4; ++tc) {
        const int cur = tc & 1;
        if (tc < 3) {
#pragma unroll
            for (int q = 0; q < 8; ++q)
                GLL16(Db + (tc + 1) * 16384 + q * 2048 + w * 512 + lane * 8,
                      &Dl[cur ^ 1][q * 2048 + w * 512]);
        }
#pragma unroll
        for (int tt = 0; tt < 8; ++tt) {
            f32x4 acc = {};
#pragma unroll
            for (int ks = 0; ks < 4; ++ks) {
                bf16x8 bF = *(const bf16x8*)&Dl[cur][swz(tt * 16 + rlo, ks * 32 + g * 8, 128)];
                acc = __builtin_amdgcn_mfma_f32_16x16x32_bf16(qF[ks], bF, acc, 0, 0, 0);
            }
            float e = evl[tc * 128 + tt * 16 + rlo];
#pragma unroll
            for (int r = 0; r < 4; ++r) {
                float sv2 = (e > 0.5f) ? acc[r] : -1e4f;
                vmax[r] = fmaxf(vmax[r], sv2);
            }
        }
        __syncthreads();
    }

    // max over the 16 token-columns held across the 16-lane group
#pragma unroll
    for (int r = 0; r < 4; ++r)
#pragma unroll
        for (int off = 1; off < 16; off <<= 1)
            vmax[r] = fmaxf(vmax[r], __shfl_xor(vmax[r], off));

    float psum = 0.f;
#pragma unroll
    for (int r = 0; r < 4; ++r)
        psum += (vmax[r] > -1000.0f) ? vmax[r] : 0.0f;

    float rtot = psum + __shfl_xor(psum, 16);
    if ((lane & 31) == 0) {
        int rr = pt * 8 + w * 2 + (g >> 1);
        out[b * R_ + rr] = rtot;
    }
}

// ---------------- launcher ----------------
extern "C" void kernel_launch(void* const* d_in, const int* in_sizes, int n_in,
                              void* d_out, int out_size, void* d_ws, size_t ws_size,
                              hipStream_t stream) {
    const float* hidden = (const float*)d_in[0];
    const int*   ctx    = (const int*)d_in[1];
    const int*   btw    = (const int*)d_in[2];
    const int*   st     = (const int*)d_in[3];
    const int*   ot     = (const int*)d_in[4];
    const int*   sf     = (const int*)d_in[5];
    const float* W      = (const float*)d_in[6];
    const float* lp     = (const float*)d_in[7];
    const float* sW     = (const float*)d_in[8];
    const float* oW     = (const float*)d_in[9];
    const float* dW     = (const float*)d_in[10];
    float* out = (float*)d_out;

    char* ws = (char*)d_ws;
    __bf16* Wt = (__bf16*)ws;                       // 196608 B (pre-swizzled)
    __bf16* D  = (__bf16*)(ws + 196608);            // 8 MB (pre-swizzled)

    k_wt  <<<(HID_ * M_) / 256, 256, 0, stream>>>(W, Wt);
    k_proj<<<(B_ * L_) / 64, 256, 0, stream>>>(hidden, Wt, D);
    k_sim <<<dim3(8, B_), 256, 0, stream>>>(lp, sW, oW, dW, st, ot, sf, ctx, btw, D, out);
}

// Round 4
// 46.085 us; speedup vs baseline: 1.4756x; 1.0913x over previous
//
#include <hip/hip_runtime.h>
#include <hip/hip_bf16.h>

typedef __attribute__((ext_vector_type(8))) __bf16 bf16x8;
typedef __attribute__((ext_vector_type(4))) float f32x4;

#define B_   64
#define L_   512
#define HID_ 768
#define M_   128
#define R_   64
#define P_   8

// XOR-swizzle for row-major LDS tiles (ushort-index units, 8-elem aligned k).
__device__ __forceinline__ int swz(int row, int k, int stride) {
    return row * stride + (k ^ ((row & 7) << 3));
}

// async 16B global -> LDS (linear dest: wave-uniform base + lane*16)
#define GLL16(gp, lp)                                                        \
    __builtin_amdgcn_global_load_lds(                                        \
        (const __attribute__((address_space(1))) void*)(gp),                 \
        (__attribute__((address_space(3))) void*)(lp), 16, 0, 0)

// ---- Kw: transpose+cast proj_W -> Wt, PRE-SWIZZLED per 64-k chunk --------
// Wt[c*8192 + n*64 + (kk ^ ((n&7)<<3))] = W[(c*64+kk)*128 + n]
__global__ __launch_bounds__(256) void k_wt(const float* __restrict__ W,
                                            __bf16* __restrict__ Wt) {
    int idx = blockIdx.x * 256 + threadIdx.x;   // k*128 + n  (coalesced read)
    int k = idx >> 7, n = idx & 127;
    int c = k >> 6, kk = k & 63;
    Wt[c * 8192 + n * 64 + (kk ^ ((n & 7) << 3))] = (__bf16)W[idx];
}

// ---- K2: D = l2norm(hidden @ W), bf16 MFMA, 2-phase pipeline -------------
// Grid dim3(B_, 8): batch b = blockIdx.x -> XCD b%8 (same XCD writes all of D_b).
// Stores D PRE-SWIZZLED: D[row*128 + (col ^ ((row&7)<<3))]
__global__ __launch_bounds__(256) void k_proj(const float* __restrict__ hidden,
                                              const __bf16* __restrict__ Wt,
                                              __bf16* __restrict__ D) {
    __shared__ __align__(16) __bf16 Al[2][64 * 64];     // 2 x 8 KB
    __shared__ __align__(16) __bf16 Bl[2][128 * 64];    // 2 x 16 KB
    const int t = threadIdx.x;
    const int lane = t & 63, w = t >> 6;
    const int rlo = lane & 15, g = lane >> 4;
    const int row0 = blockIdx.x * 512 + blockIdx.y * 64;   // b*512 + tc*64

    f32x4 acc[8] = {};

    const int ar = t >> 2;            // A stage: row 0..63
    const int ac = (t & 3) * 16;      //          k offset 0/16/32/48
    const float* arow = hidden + (size_t)(row0 + ar) * HID_ + ac;

    // ---- prologue: stage chunk 0 into buffer 0 ----
#pragma unroll
    for (int q = 0; q < 4; ++q)
        GLL16(Wt + q * 2048 + w * 512 + lane * 8, &Bl[0][q * 2048 + w * 512]);
    {
        float4 f0 = ((const float4*)arow)[0];
        float4 f1 = ((const float4*)arow)[1];
        float4 f2 = ((const float4*)arow)[2];
        float4 f3 = ((const float4*)arow)[3];
        bf16x8 v0, v1;
        v0[0]=(__bf16)f0.x; v0[1]=(__bf16)f0.y; v0[2]=(__bf16)f0.z; v0[3]=(__bf16)f0.w;
        v0[4]=(__bf16)f1.x; v0[5]=(__bf16)f1.y; v0[6]=(__bf16)f1.z; v0[7]=(__bf16)f1.w;
        v1[0]=(__bf16)f2.x; v1[1]=(__bf16)f2.y; v1[2]=(__bf16)f2.z; v1[3]=(__bf16)f2.w;
        v1[4]=(__bf16)f3.x; v1[5]=(__bf16)f3.y; v1[6]=(__bf16)f3.z; v1[7]=(__bf16)f3.w;
        *(bf16x8*)&Al[0][swz(ar, ac,     64)] = v0;
        *(bf16x8*)&Al[0][swz(ar, ac + 8, 64)] = v1;
    }
    __syncthreads();

    for (int ci = 0; ci < 12; ++ci) {
        const int cur = ci & 1;
        const bool pre = ci < 11;
        float4 f0, f1, f2, f3;
        if (pre) {   // issue next-chunk loads BEFORE compute
#pragma unroll
            for (int q = 0; q < 4; ++q)
                GLL16(Wt + (ci + 1) * 8192 + q * 2048 + w * 512 + lane * 8,
                      &Bl[cur ^ 1][q * 2048 + w * 512]);
            const float* src = arow + (ci + 1) * 64;
            f0 = ((const float4*)src)[0];
            f1 = ((const float4*)src)[1];
            f2 = ((const float4*)src)[2];
            f3 = ((const float4*)src)[3];
        }
#pragma unroll
        for (int s = 0; s < 2; ++s) {
            int k = s * 32 + g * 8;
            bf16x8 aF = *(const bf16x8*)&Al[cur][swz(w * 16 + rlo, k, 64)];
#pragma unroll
            for (int c = 0; c < 8; ++c) {
                bf16x8 bF = *(const bf16x8*)&Bl[cur][swz(c * 16 + rlo, k, 64)];
                acc[c] = __builtin_amdgcn_mfma_f32_16x16x32_bf16(aF, bF, acc[c], 0, 0, 0);
            }
        }
        if (pre) {   // write-late: cvt + ds_write after compute
            bf16x8 v0, v1;
            v0[0]=(__bf16)f0.x; v0[1]=(__bf16)f0.y; v0[2]=(__bf16)f0.z; v0[3]=(__bf16)f0.w;
            v0[4]=(__bf16)f1.x; v0[5]=(__bf16)f1.y; v0[6]=(__bf16)f1.z; v0[7]=(__bf16)f1.w;
            v1[0]=(__bf16)f2.x; v1[1]=(__bf16)f2.y; v1[2]=(__bf16)f2.z; v1[3]=(__bf16)f2.w;
            v1[4]=(__bf16)f3.x; v1[5]=(__bf16)f3.y; v1[6]=(__bf16)f3.z; v1[7]=(__bf16)f3.w;
            *(bf16x8*)&Al[cur ^ 1][swz(ar, ac,     64)] = v0;
            *(bf16x8*)&Al[cur ^ 1][swz(ar, ac + 8, 64)] = v1;
        }
        __syncthreads();
    }

    // L2-normalize each output row, store bf16 PRE-SWIZZLED
    float ss[4] = {0.f, 0.f, 0.f, 0.f};
#pragma unroll
    for (int c = 0; c < 8; ++c)
#pragma unroll
        for (int r = 0; r < 4; ++r) ss[r] += acc[c][r] * acc[c][r];
#pragma unroll
    for (int r = 0; r < 4; ++r)
#pragma unroll
        for (int off = 1; off < 16; off <<= 1) ss[r] += __shfl_xor(ss[r], off);
    float sc[4];
#pragma unroll
    for (int r = 0; r < 4; ++r) sc[r] = 1.0f / fmaxf(sqrtf(ss[r]), 1e-12f);
#pragma unroll
    for (int c = 0; c < 8; ++c)
#pragma unroll
        for (int r = 0; r < 4; ++r) {
            int row = row0 + w * 16 + g * 4 + r;
            int col = c * 16 + rlo;
            D[(size_t)row * M_ + (col ^ ((row & 7) << 3))] = (__bf16)(acc[c][r] * sc[r]);
        }
}

// ---- K3: fused probes + evidence + sim + masked max + sum -> logits ------
// Grid dim3(B_, 8): batch b = blockIdx.x -> same XCD b%8 as k_proj's D_b writes,
// so D reads hit that XCD's L2 instead of re-fetching from HBM on 8 XCDs.
__global__ __launch_bounds__(256) void k_sim(const float* __restrict__ lp,
                                             const float* __restrict__ sW,
                                             const float* __restrict__ oW,
                                             const float* __restrict__ dW,
                                             const int* __restrict__ st,
                                             const int* __restrict__ ot,
                                             const int* __restrict__ sf,
                                             const int* __restrict__ ctx,
                                             const int* __restrict__ btw,
                                             const __bf16* __restrict__ D,
                                             float* __restrict__ out) {
    __shared__ __align__(16) __bf16 Dl[2][128 * 128];   // 2 x 32 KB
    __shared__ float evl[L_];
    __shared__ int anyf;
    const int t = threadIdx.x;
    const int lane = t & 63, w = t >> 6;
    const int rlo = lane & 15, g = lane >> 4;
    const int b = blockIdx.x, pt = blockIdx.y;

    const __bf16* Db = D + (size_t)b * L_ * M_;

    // ---- issue chunk-0 DMA first (overlaps probe build) ----
#pragma unroll
    for (int q = 0; q < 8; ++q)
        GLL16(Db + q * 2048 + w * 512 + lane * 8, &Dl[0][q * 2048 + w * 512]);

    // ---- evidence (fused) ----
    if (t == 0) anyf = 0;
    __syncthreads();
    int v0 = btw[b * L_ + t], v1 = btw[b * L_ + t + 256];
    int c0 = ctx[b * L_ + t], c1 = ctx[b * L_ + t + 256];
    if (v0 | v1) anyf = 1;          // benign race: all writers store 1
    __syncthreads();
    const int any = anyf;
    evl[t]       = (any ? v0 : c0) ? 1.0f : 0.0f;
    evl[t + 256] = (any ? v1 : c1) ? 1.0f : 0.0f;

    // ---- probe build (fused, in-register) ----
    const int sb = st[b], ob = ot[b], db = sf[b];
    const float* lpp = lp + (size_t)(pt * 64 + w * 16 + rlo) * M_;
    const float* sv  = sW + sb * M_;
    const float* ov  = oW + ob * M_;
    const float* dv  = dW + db * M_;
    float qv[32];
    float ssq = 0.f;
#pragma unroll
    for (int ks = 0; ks < 4; ++ks) {
        const int m0 = ks * 32 + g * 8;
#pragma unroll
        for (int h = 0; h < 2; ++h) {
            float4 a  = *(const float4*)(lpp + m0 + h * 4);
            float4 s4 = *(const float4*)(sv  + m0 + h * 4);
            float4 o4 = *(const float4*)(ov  + m0 + h * 4);
            float4 d4 = *(const float4*)(dv  + m0 + h * 4);
            float x0 = a.x + s4.x + o4.x + d4.x;
            float x1 = a.y + s4.y + o4.y + d4.y;
            float x2 = a.z + s4.z + o4.z + d4.z;
            float x3 = a.w + s4.w + o4.w + d4.w;
            qv[ks * 8 + h * 4 + 0] = x0;
            qv[ks * 8 + h * 4 + 1] = x1;
            qv[ks * 8 + h * 4 + 2] = x2;
            qv[ks * 8 + h * 4 + 3] = x3;
            ssq += x0 * x0 + x1 * x1 + x2 * x2 + x3 * x3;
        }
    }
    ssq += __shfl_xor(ssq, 16);
    ssq += __shfl_xor(ssq, 32);
    const float scq = 1.0f / fmaxf(sqrtf(ssq), 1e-12f);
    bf16x8 qF[4];
#pragma unroll
    for (int ks = 0; ks < 4; ++ks)
#pragma unroll
        for (int j = 0; j < 8; ++j)
            qF[ks][j] = (__bf16)(qv[ks * 8 + j] * scq);

    __syncthreads();   // Dl[0] + evl ready

    // ---- MaxSim main loop: 1 barrier/chunk, DMA next while computing ----
    float vmax[4] = {-1e30f, -1e30f, -1e30f, -1e30f};

    for (int tc = 0; tc < 4; ++tc) {
        const int cur = tc & 1;
        if (tc < 3) {
#pragma unroll
            for (int q = 0; q < 8; ++q)
                GLL16(Db + (tc + 1) * 16384 + q * 2048 + w * 512 + lane * 8,
                      &Dl[cur ^ 1][q * 2048 + w * 512]);
        }
#pragma unroll
        for (int tt = 0; tt < 8; ++tt) {
            f32x4 acc = {};
#pragma unroll
            for (int ks = 0; ks < 4; ++ks) {
                bf16x8 bF = *(const bf16x8*)&Dl[cur][swz(tt * 16 + rlo, ks * 32 + g * 8, 128)];
                acc = __builtin_amdgcn_mfma_f32_16x16x32_bf16(qF[ks], bF, acc, 0, 0, 0);
            }
            float e = evl[tc * 128 + tt * 16 + rlo];
#pragma unroll
            for (int r = 0; r < 4; ++r) {
                float sv2 = (e > 0.5f) ? acc[r] : -1e4f;
                vmax[r] = fmaxf(vmax[r], sv2);
            }
        }
        __syncthreads();
    }

    // max over the 16 token-columns held across the 16-lane group
#pragma unroll
    for (int r = 0; r < 4; ++r)
#pragma unroll
        for (int off = 1; off < 16; off <<= 1)
            vmax[r] = fmaxf(vmax[r], __shfl_xor(vmax[r], off));

    float psum = 0.f;
#pragma unroll
    for (int r = 0; r < 4; ++r)
        psum += (vmax[r] > -1000.0f) ? vmax[r] : 0.0f;

    float rtot = psum + __shfl_xor(psum, 16);
    if ((lane & 31) == 0) {
        int rr = pt * 8 + w * 2 + (g >> 1);
        out[b * R_ + rr] = rtot;
    }
}

// ---------------- launcher ----------------
extern "C" void kernel_launch(void* const* d_in, const int* in_sizes, int n_in,
                              void* d_out, int out_size, void* d_ws, size_t ws_size,
                              hipStream_t stream) {
    const float* hidden = (const float*)d_in[0];
    const int*   ctx    = (const int*)d_in[1];
    const int*   btw    = (const int*)d_in[2];
    const int*   st     = (const int*)d_in[3];
    const int*   ot     = (const int*)d_in[4];
    const int*   sf     = (const int*)d_in[5];
    const float* W      = (const float*)d_in[6];
    const float* lp     = (const float*)d_in[7];
    const float* sW     = (const float*)d_in[8];
    const float* oW     = (const float*)d_in[9];
    const float* dW     = (const float*)d_in[10];
    float* out = (float*)d_out;

    char* ws = (char*)d_ws;
    __bf16* Wt = (__bf16*)ws;                       // 196608 B (pre-swizzled)
    __bf16* D  = (__bf16*)(ws + 196608);            // 8 MB (pre-swizzled)

    k_wt  <<<(HID_ * M_) / 256, 256, 0, stream>>>(W, Wt);
    k_proj<<<dim3(B_, 8), 256, 0, stream>>>(hidden, Wt, D);
    k_sim <<<dim3(B_, 8), 256, 0, stream>>>(lp, sW, oW, dW, st, ot, sf, ctx, btw, D, out);
}

// Round 5
// 44.011 us; speedup vs baseline: 1.5451x; 1.0471x over previous
//
#include <hip/hip_runtime.h>
#include <hip/hip_bf16.h>

typedef __attribute__((ext_vector_type(8))) __bf16 bf16x8;
typedef __attribute__((ext_vector_type(4))) float f32x4;

#define B_   64
#define L_   512
#define HID_ 768
#define M_   128
#define R_   64
#define P_   8

// XOR-swizzle for row-major LDS tiles (ushort-index units, 8-elem aligned k).
__device__ __forceinline__ int swz(int row, int k, int stride) {
    return row * stride + (k ^ ((row & 7) << 3));
}

// async 16B global -> LDS (linear dest: wave-uniform base + lane*16)
#define GLL16(gp, lp)                                                        \
    __builtin_amdgcn_global_load_lds(                                        \
        (const __attribute__((address_space(1))) void*)(gp),                 \
        (__attribute__((address_space(3))) void*)(lp), 16, 0, 0)

// ---- Kw: transpose+cast proj_W -> Wt, PRE-SWIZZLED per 64-k chunk --------
__global__ __launch_bounds__(256) void k_wt(const float* __restrict__ W,
                                            __bf16* __restrict__ Wt) {
    int idx = blockIdx.x * 256 + threadIdx.x;   // k*128 + n  (coalesced read)
    int k = idx >> 7, n = idx & 127;
    int c = k >> 6, kk = k & 63;
    Wt[c * 8192 + n * 64 + (kk ^ ((n & 7) << 3))] = (__bf16)W[idx];
}

// ---- K2: D = l2norm(hidden @ W), bf16 MFMA, 2-phase pipeline -------------
// 512 threads: 8 waves = 4 row-blocks x 2 col-halves. 4 waves/SIMD.
// Grid dim3(B_, 8): batch b = blockIdx.x -> XCD b%8.
// Stores D PRE-SWIZZLED: D[row*128 + (col ^ ((row&7)<<3))]
__global__ __launch_bounds__(512, 4) void k_proj(const float* __restrict__ hidden,
                                                 const __bf16* __restrict__ Wt,
                                                 __bf16* __restrict__ D) {
    __shared__ __align__(16) __bf16 Al[2][64 * 64];     // 2 x 8 KB
    __shared__ __align__(16) __bf16 Bl[2][128 * 64];    // 2 x 16 KB
    __shared__ float nbuf[2][64];
    const int t = threadIdx.x;
    const int lane = t & 63, w = t >> 6;
    const int rlo = lane & 15, g = lane >> 4;
    const int rb = w & 3, ch = w >> 2;      // row-block 0..3, col-half 0..1
    const int row0 = blockIdx.x * 512 + blockIdx.y * 64;   // b*512 + j*64

    f32x4 acc[4] = {};

    const int ar = t >> 3;            // A stage: row 0..63 (8 threads/row)
    const int ac = (t & 7) * 8;       //          k offset, step 8
    const float* arow = hidden + (size_t)(row0 + ar) * HID_ + ac;

    // ---- prologue: stage chunk 0 into buffer 0 ----
    GLL16(Wt + w * 1024 + lane * 8,       &Bl[0][w * 1024]);
    GLL16(Wt + w * 1024 + 512 + lane * 8, &Bl[0][w * 1024 + 512]);
    {
        float4 f0 = *(const float4*)(arow);
        float4 f1 = *(const float4*)(arow + 4);
        bf16x8 v;
        v[0]=(__bf16)f0.x; v[1]=(__bf16)f0.y; v[2]=(__bf16)f0.z; v[3]=(__bf16)f0.w;
        v[4]=(__bf16)f1.x; v[5]=(__bf16)f1.y; v[6]=(__bf16)f1.z; v[7]=(__bf16)f1.w;
        *(bf16x8*)&Al[0][swz(ar, ac, 64)] = v;
    }
    __syncthreads();

    for (int ci = 0; ci < 12; ++ci) {
        const int cur = ci & 1;
        const bool pre = ci < 11;
        float4 f0, f1;
        if (pre) {   // issue next-chunk loads BEFORE compute
            const __bf16* wsrc = Wt + (ci + 1) * 8192 + w * 1024;
            GLL16(wsrc + lane * 8,       &Bl[cur ^ 1][w * 1024]);
            GLL16(wsrc + 512 + lane * 8, &Bl[cur ^ 1][w * 1024 + 512]);
            const float* src = arow + (ci + 1) * 64;
            f0 = *(const float4*)(src);
            f1 = *(const float4*)(src + 4);
        }
#pragma unroll
        for (int s = 0; s < 2; ++s) {
            int kk = s * 32 + g * 8;
            bf16x8 aF = *(const bf16x8*)&Al[cur][swz(rb * 16 + rlo, kk, 64)];
#pragma unroll
            for (int c = 0; c < 4; ++c) {
                bf16x8 bF = *(const bf16x8*)&Bl[cur][swz(ch * 64 + c * 16 + rlo, kk, 64)];
                acc[c] = __builtin_amdgcn_mfma_f32_16x16x32_bf16(aF, bF, acc[c], 0, 0, 0);
            }
        }
        if (pre) {   // write-late: cvt + ds_write after compute
            bf16x8 v;
            v[0]=(__bf16)f0.x; v[1]=(__bf16)f0.y; v[2]=(__bf16)f0.z; v[3]=(__bf16)f0.w;
            v[4]=(__bf16)f1.x; v[5]=(__bf16)f1.y; v[6]=(__bf16)f1.z; v[7]=(__bf16)f1.w;
            *(bf16x8*)&Al[cur ^ 1][swz(ar, ac, 64)] = v;
        }
        __syncthreads();
    }

    // ---- norm: partial over this wave's 64 cols, exchange across halves ----
    float ss[4] = {0.f, 0.f, 0.f, 0.f};
#pragma unroll
    for (int c = 0; c < 4; ++c)
#pragma unroll
        for (int r = 0; r < 4; ++r) ss[r] += acc[c][r] * acc[c][r];
#pragma unroll
    for (int r = 0; r < 4; ++r)
#pragma unroll
        for (int off = 1; off < 16; off <<= 1) ss[r] += __shfl_xor(ss[r], off);
    if (rlo == 0) {
#pragma unroll
        for (int r = 0; r < 4; ++r) nbuf[ch][rb * 16 + g * 4 + r] = ss[r];
    }
    __syncthreads();
    float sc[4];
#pragma unroll
    for (int r = 0; r < 4; ++r) {
        float tot = nbuf[0][rb * 16 + g * 4 + r] + nbuf[1][rb * 16 + g * 4 + r];
        sc[r] = 1.0f / fmaxf(sqrtf(tot), 1e-12f);
    }

    // ---- repack into LDS (pre-swizzled), then coalesced vector store ----
    __bf16* Dst = (__bf16*)Al;     // 16 KB, free after last chunk barrier
#pragma unroll
    for (int c = 0; c < 4; ++c)
#pragma unroll
        for (int r = 0; r < 4; ++r) {
            int row = rb * 16 + g * 4 + r;
            int col = ch * 64 + c * 16 + rlo;
            Dst[row * 128 + (col ^ ((row & 7) << 3))] = (__bf16)(acc[c][r] * sc[r]);
        }
    __syncthreads();
#pragma unroll
    for (int h = 0; h < 2; ++h) {
        int row = (t >> 4) + h * 32;
        int seg = t & 15;
        bf16x8 v = *(const bf16x8*)&Dst[row * 128 + seg * 8];
        *(bf16x8*)(D + (size_t)(row0 + row) * M_ + seg * 8) = v;
    }
}

// ---- K3: fused probes + evidence + sim + masked max + sum -> logits ------
// Grid dim3(B_, 8): batch b = blockIdx.x -> same XCD b%8 as k_proj's D_b writes.
__global__ __launch_bounds__(256) void k_sim(const float* __restrict__ lp,
                                             const float* __restrict__ sW,
                                             const float* __restrict__ oW,
                                             const float* __restrict__ dW,
                                             const int* __restrict__ st,
                                             const int* __restrict__ ot,
                                             const int* __restrict__ sf,
                                             const int* __restrict__ ctx,
                                             const int* __restrict__ btw,
                                             const __bf16* __restrict__ D,
                                             float* __restrict__ out) {
    __shared__ __align__(16) __bf16 Dl[2][128 * 128];   // 2 x 32 KB
    __shared__ float evl[L_];
    __shared__ int anyf;
    const int t = threadIdx.x;
    const int lane = t & 63, w = t >> 6;
    const int rlo = lane & 15, g = lane >> 4;
    const int b = blockIdx.x, pt = blockIdx.y;

    const __bf16* Db = D + (size_t)b * L_ * M_;

    // ---- issue chunk-0 DMA first (overlaps probe build) ----
#pragma unroll
    for (int q = 0; q < 8; ++q)
        GLL16(Db + q * 2048 + w * 512 + lane * 8, &Dl[0][q * 2048 + w * 512]);

    // ---- evidence (fused) ----
    if (t == 0) anyf = 0;
    __syncthreads();
    int v0 = btw[b * L_ + t], v1 = btw[b * L_ + t + 256];
    int c0 = ctx[b * L_ + t], c1 = ctx[b * L_ + t + 256];
    if (v0 | v1) anyf = 1;          // benign race: all writers store 1
    __syncthreads();
    const int any = anyf;
    evl[t]       = (any ? v0 : c0) ? 1.0f : 0.0f;
    evl[t + 256] = (any ? v1 : c1) ? 1.0f : 0.0f;

    // ---- probe build (fused, in-register) ----
    const int sb = st[b], ob = ot[b], db = sf[b];
    const float* lpp = lp + (size_t)(pt * 64 + w * 16 + rlo) * M_;
    const float* sv  = sW + sb * M_;
    const float* ov  = oW + ob * M_;
    const float* dv  = dW + db * M_;
    float qv[32];
    float ssq = 0.f;
#pragma unroll
    for (int ks = 0; ks < 4; ++ks) {
        const int m0 = ks * 32 + g * 8;
#pragma unroll
        for (int h = 0; h < 2; ++h) {
            float4 a  = *(const float4*)(lpp + m0 + h * 4);
            float4 s4 = *(const float4*)(sv  + m0 + h * 4);
            float4 o4 = *(const float4*)(ov  + m0 + h * 4);
            float4 d4 = *(const float4*)(dv  + m0 + h * 4);
            float x0 = a.x + s4.x + o4.x + d4.x;
            float x1 = a.y + s4.y + o4.y + d4.y;
            float x2 = a.z + s4.z + o4.z + d4.z;
            float x3 = a.w + s4.w + o4.w + d4.w;
            qv[ks * 8 + h * 4 + 0] = x0;
            qv[ks * 8 + h * 4 + 1] = x1;
            qv[ks * 8 + h * 4 + 2] = x2;
            qv[ks * 8 + h * 4 + 3] = x3;
            ssq += x0 * x0 + x1 * x1 + x2 * x2 + x3 * x3;
        }
    }
    ssq += __shfl_xor(ssq, 16);
    ssq += __shfl_xor(ssq, 32);
    const float scq = 1.0f / fmaxf(sqrtf(ssq), 1e-12f);
    bf16x8 qF[4];
#pragma unroll
    for (int ks = 0; ks < 4; ++ks)
#pragma unroll
        for (int j = 0; j < 8; ++j)
            qF[ks][j] = (__bf16)(qv[ks * 8 + j] * scq);

    __syncthreads();   // Dl[0] + evl ready

    // ---- MaxSim main loop: 1 barrier/chunk, DMA next while computing ----
    float vmax[4] = {-1e30f, -1e30f, -1e30f, -1e30f};

    for (int tc = 0; tc < 4; ++tc) {
        const int cur = tc & 1;
        if (tc < 3) {
#pragma unroll
            for (int q = 0; q < 8; ++q)
                GLL16(Db + (tc + 1) * 16384 + q * 2048 + w * 512 + lane * 8,
                      &Dl[cur ^ 1][q * 2048 + w * 512]);
        }
#pragma unroll
        for (int tt = 0; tt < 8; ++tt) {
            f32x4 acc = {};
#pragma unroll
            for (int ks = 0; ks < 4; ++ks) {
                bf16x8 bF = *(const bf16x8*)&Dl[cur][swz(tt * 16 + rlo, ks * 32 + g * 8, 128)];
                acc = __builtin_amdgcn_mfma_f32_16x16x32_bf16(qF[ks], bF, acc, 0, 0, 0);
            }
            float e = evl[tc * 128 + tt * 16 + rlo];
#pragma unroll
            for (int r = 0; r < 4; ++r) {
                float sv2 = (e > 0.5f) ? acc[r] : -1e4f;
                vmax[r] = fmaxf(vmax[r], sv2);
            }
        }
        __syncthreads();
    }

    // max over the 16 token-columns held across the 16-lane group
#pragma unroll
    for (int r = 0; r < 4; ++r)
#pragma unroll
        for (int off = 1; off < 16; off <<= 1)
            vmax[r] = fmaxf(vmax[r], __shfl_xor(vmax[r], off));

    float psum = 0.f;
#pragma unroll
    for (int r = 0; r < 4; ++r)
        psum += (vmax[r] > -1000.0f) ? vmax[r] : 0.0f;

    float rtot = psum + __shfl_xor(psum, 16);
    if ((lane & 31) == 0) {
        int rr = pt * 8 + w * 2 + (g >> 1);
        out[b * R_ + rr] = rtot;
    }
}

// ---------------- launcher ----------------
extern "C" void kernel_launch(void* const* d_in, const int* in_sizes, int n_in,
                              void* d_out, int out_size, void* d_ws, size_t ws_size,
                              hipStream_t stream) {
    const float* hidden = (const float*)d_in[0];
    const int*   ctx    = (const int*)d_in[1];
    const int*   btw    = (const int*)d_in[2];
    const int*   st     = (const int*)d_in[3];
    const int*   ot     = (const int*)d_in[4];
    const int*   sf     = (const int*)d_in[5];
    const float* W      = (const float*)d_in[6];
    const float* lp     = (const float*)d_in[7];
    const float* sW     = (const float*)d_in[8];
    const float* oW     = (const float*)d_in[9];
    const float* dW     = (const float*)d_in[10];
    float* out = (float*)d_out;

    char* ws = (char*)d_ws;
    __bf16* Wt = (__bf16*)ws;                       // 196608 B (pre-swizzled)
    __bf16* D  = (__bf16*)(ws + 196608);            // 8 MB (pre-swizzled)

    k_wt  <<<(HID_ * M_) / 256, 256, 0, stream>>>(W, Wt);
    k_proj<<<dim3(B_, 8), 512, 0, stream>>>(hidden, Wt, D);
    k_sim <<<dim3(B_, 8), 256, 0, stream>>>(lp, sW, oW, dW, st, ot, sf, ctx, btw, D, out);
}